// Round 5
// baseline (260.894 us; speedup 1.0000x reference)
//
#include <hip/hip_runtime.h>
#include <hip/hip_bf16.h>

// B=2, H=96, W=128, D=64, C=32, F=32, kernel 3x3x3, pad 1 in h/w, depth-shifted.
#define Bn 2
#define Hn 96
#define Wn 128
#define Dn 64
#define Cn 32
#define Fn 32
#define TW 8            // w-pixels per block (one per wave)
#define NCOL (TW + 2)   // staged neighbor columns

typedef short bf16x8 __attribute__((ext_vector_type(8)));
typedef float f32x4  __attribute__((ext_vector_type(4)));

__device__ __forceinline__ ushort f2bf(float x) {
    __hip_bfloat16 h = __float2bfloat16(x);   // RNE
    return *reinterpret_cast<ushort*>(&h);
}

// Rows are 32 shorts (64B) = 4 slots of 16B. slot' = slot ^ ((r>>1)&3):
// 16 consecutive rows at the same slot spread over all 8 bank-quads (2-way = free).
__device__ __forceinline__ int swz_off(int r, int slot) {
    return r * 32 + ((slot ^ ((r >> 1) & 3)) << 3);
}

// ---- prep: transpose kernel weights to bf16 kT[27][f][c] in workspace
__global__ void prep_kT(const float* __restrict__ kern, ushort* __restrict__ kT) {
    const int e = blockIdx.x * 256 + threadIdx.x;    // 27*32*32 = 27648
    if (e >= 27 * Cn * Fn) return;
    const int c  = e & 31;
    const int f  = (e >> 5) & 31;
    const int kk = e >> 10;
    kT[e] = f2bf(kern[kk * (Cn * Fn) + c * Fn + f]);
}

__global__ __launch_bounds__(512, 8) void sconv3d_mfma(
    const float*  __restrict__ img,   // [B,H,W,D,C]
    const int*    __restrict__ bp,    // [B,H,W]
    const float*  __restrict__ kern,  // [3,3,3,C,F] (fp32, for dv path)
    const ushort* __restrict__ kT,    // [27][F][C] bf16
    const float*  __restrict__ dvp,
    float*        __restrict__ out)   // [B,H,W,D,F]
{
    // image columns, bf16, [col][row 0..63][c], swizzled 16B slots. 40960 B exactly
    // -> 4 blocks/CU (160 KB exact fit), 32 waves/CU theoretical.
    __shared__ ushort colS[NCOL * Dn * Cn];

    const int blk = blockIdx.x;                      // (b*Hn + h)*(Wn/TW) + wt
    const int wt  = blk % (Wn / TW);
    const int bh  = blk / (Wn / TW);
    const int h   = bh % Hn;
    const int b   = bh / Hn;
    const int w0  = wt * TW;

    const int tid  = threadIdx.x;
    const int lane = tid & 63;
    const int wave = tid >> 6;                       // 0..7
    const int w    = w0 + wave;                      // this wave's pixel

    const int lrow = lane & 15;                      // A row / B f-col
    const int lgrp = lane >> 4;                      // 16B k-slot

    const float dv  = *dvp;
    const int   bpc = bp[(b * Hn + h) * Wn + w];

    // staging write coords (ushort4 = 8B per thread; 512 thr x 4 floats = 1 column)
    const int st_r    = tid >> 3;                    // row 0..63
    const int st_slot = (tid >> 1) & 3;
    const int st_lo   = (tid & 1) * 4;
    const int st_off  = swz_off(st_r, st_slot) + st_lo;

    f32x4 acc[4][2];
#pragma unroll
    for (int i = 0; i < 4; ++i)
#pragma unroll
        for (int j = 0; j < 2; ++j) acc[i][j] = (f32x4)0.f;

    for (int kh = 0; kh < 3; ++kh) {
        const int  hh     = h + kh - 1;
        const bool hvalid = (hh >= 0) && (hh < Hn);

        // hoist this kh's depth shifts: latency hides under staging phase
        int sh[3];
#pragma unroll
        for (int kw = 0; kw < 3; ++kw) {
            const int wc = w - 1 + kw;
            sh[kw] = (hvalid && wc >= 0 && wc < Wn)
                       ? (bpc - bp[(b * Hn + hh) * Wn + wc]) : 0;
        }

        __syncthreads();   // previous iteration's compute done before restage
        if (hvalid) {
            for (int j = 0; j < NCOL; ++j) {
                const int wc = w0 - 1 + j;
                if (wc < 0 || wc >= Wn) continue;
                const float4 v = *(const float4*)(img +
                    (size_t)((b * Hn + hh) * Wn + wc) * (Dn * Cn) + tid * 4);
                ushort4 u;
                u.x = f2bf(v.x); u.y = f2bf(v.y); u.z = f2bf(v.z); u.w = f2bf(v.w);
                *(ushort4*)&colS[j * (Dn * Cn) + st_off] = u;
            }
        }
        __syncthreads();
        if (!hvalid) continue;

        for (int kw = 0; kw < 3; ++kw) {
            const int wc = w - 1 + kw;
            if (wc < 0 || wc >= Wn) continue;         // sp_valid false -> contributes dv(=0)
            const ushort* colp = &colS[(wc - (w0 - 1)) * (Dn * Cn)];
#pragma unroll
            for (int kd = 0; kd < 3; ++kd) {
                const int kk = (kh * 3 + kw) * 3 + kd;
                // B frags from global (L1/L2-resident, static addresses)
                const bf16x8 bf0 = *(const bf16x8*)&kT[(kk * Fn + lrow)      * Cn + lgrp * 8];
                const bf16x8 bf1 = *(const bf16x8*)&kT[(kk * Fn + lrow + 16) * Cn + lgrp * 8];
                const int X = sh[kw] + kd - 1;        // depth shift for this tap
                __builtin_amdgcn_s_setprio(1);
#pragma unroll
                for (int dt = 0; dt < 4; ++dt) {
                    const int  idx   = dt * 16 + lrow + X;
                    const int  ci    = idx < 0 ? 0 : (idx > 63 ? 63 : idx);  // med3
                    const bool valid = (idx == ci);
                    bf16x8 af = *(const bf16x8*)&colp[swz_off(ci, lgrp)];
                    if (!valid) af = (bf16x8)0;       // OOB depth -> zero (dv=0 path)
                    acc[dt][0] = __builtin_amdgcn_mfma_f32_16x16x32_bf16(af, bf0, acc[dt][0], 0, 0, 0);
                    acc[dt][1] = __builtin_amdgcn_mfma_f32_16x16x32_bf16(af, bf1, acc[dt][1], 0, 0, 0);
                }
                __builtin_amdgcn_s_setprio(0);
            }
        }
    }

    // ---- dv != 0 correction (dead for this benchmark; keeps semantics general)
    if (dv != 0.0f) {
        for (int kh = 0; kh < 3; ++kh) {
            const int hh = h + kh - 1;
            const bool hv = (hh >= 0) && (hh < Hn);
            for (int kw = 0; kw < 3; ++kw) {
                const int wc = w - 1 + kw;
                const bool sp = hv && (wc >= 0) && (wc < Wn);
                const int s = sp ? (bpc - bp[(b * Hn + hh) * Wn + wc]) : 0;
                for (int kd = 0; kd < 3; ++kd) {
                    float ks0 = 0.f, ks1 = 0.f;
                    for (int c = 0; c < Cn; ++c) {
                        const float* kp = kern + (size_t)(((kh * 3 + kw) * 3 + kd) * Cn + c) * Fn;
                        ks0 += kp[lrow];
                        ks1 += kp[16 + lrow];
                    }
                    for (int dt = 0; dt < 4; ++dt)
                        for (int j = 0; j < 4; ++j) {
                            const int d   = dt * 16 + lgrp * 4 + j;
                            const int idx = d + s + kd - 1;
                            const bool valid = sp && (idx >= 0) && (idx < Dn);
                            if (!valid) { acc[dt][0][j] += dv * ks0; acc[dt][1][j] += dv * ks1; }
                        }
                }
            }
        }
    }

    // ---- epilogue: D lane l reg j -> d = dt*16 + lgrp*4 + j, f = ft*16 + lrow
    const size_t pixbase = ((size_t)(b * Hn + h) * Wn + w) * (Dn * Fn);
#pragma unroll
    for (int dt = 0; dt < 4; ++dt)
#pragma unroll
        for (int ft = 0; ft < 2; ++ft)
#pragma unroll
            for (int j = 0; j < 4; ++j) {
                const int d = dt * 16 + lgrp * 4 + j;
                const int f = ft * 16 + lrow;
                out[pixbase + d * Fn + f] = acc[dt][ft][j];
            }
}

extern "C" void kernel_launch(void* const* d_in, const int* in_sizes, int n_in,
                              void* d_out, int out_size, void* d_ws, size_t ws_size,
                              hipStream_t stream) {
    const float* img  = (const float*)d_in[0];
    const int*   bp   = (const int*)d_in[1];
    const float* kern = (const float*)d_in[2];
    const float* dvp  = (const float*)d_in[3];
    float* out = (float*)d_out;
    ushort* kT = (ushort*)d_ws;                      // 27*32*32*2 = 55296 B

    hipLaunchKernelGGL(prep_kT, dim3(108), dim3(256), 0, stream, kern, kT);

    const int nblk = Bn * Hn * (Wn / TW);            // 3072
    hipLaunchKernelGGL(sconv3d_mfma, dim3(nblk), dim3(512), 0, stream,
                       img, bp, kern, kT, dvp, out);
}

// Round 6
// 184.823 us; speedup vs baseline: 1.4116x; 1.4116x over previous
//
#include <hip/hip_runtime.h>
#include <hip/hip_bf16.h>

// B=2, H=96, W=128, D=64, C=32, F=32, kernel 3x3x3, pad 1 in h/w, depth-shifted.
#define Bn 2
#define Hn 96
#define Wn 128
#define Dn 64
#define Cn 32
#define Fn 32
#define TH 2                 // patch: 2 h-rows
#define TW 8                 // patch: 8 w-cols  -> 16 pixels, one per wave
#define CH (TH + 2)          // 4 staged h-rows
#define CW (TW + 2)          // 10 staged w-cols
#define NCOLS (CH * CW)      // 40 columns x 4KB bf16 = 163840 B LDS (exact CU max)

typedef short bf16x8 __attribute__((ext_vector_type(8)));
typedef float f32x4  __attribute__((ext_vector_type(4)));

__device__ __forceinline__ ushort f2bf(float x) {
    __hip_bfloat16 h = __float2bfloat16(x);   // RNE
    return *reinterpret_cast<ushort*>(&h);
}

// Rows are 32 shorts (64B) = 4 slots of 16B. slot' = slot ^ ((r>>1)&3):
// 16 consecutive rows at the same slot spread over all 8 bank-quads (2-way = free).
__device__ __forceinline__ int swz_off(int r, int slot) {
    return r * 32 + ((slot ^ ((r >> 1) & 3)) << 3);
}

// ---- prep: transpose kernel weights to bf16 kT[27][f][c] in workspace
__global__ void prep_kT(const float* __restrict__ kern, ushort* __restrict__ kT) {
    const int e = blockIdx.x * 256 + threadIdx.x;    // 27*32*32 = 27648
    if (e >= 27 * Cn * Fn) return;
    const int c  = e & 31;
    const int f  = (e >> 5) & 31;
    const int kk = e >> 10;
    kT[e] = f2bf(kern[kk * (Cn * Fn) + c * Fn + f]);
}

__global__ __launch_bounds__(1024, 4) void sconv3d_mfma(
    const float*  __restrict__ img,   // [B,H,W,D,C]
    const int*    __restrict__ bp,    // [B,H,W]
    const float*  __restrict__ kern,  // [3,3,3,C,F] (fp32, for dv path)
    const ushort* __restrict__ kT,    // [27][F][C] bf16
    const float*  __restrict__ dvp,
    float*        __restrict__ out)   // [B,H,W,D,F]
{
    // 40 halo columns, bf16 [col][d 0..63][c], swizzled 16B slots.
    __shared__ ushort colS[NCOLS * Dn * Cn];         // 163840 B

    const int blk = blockIdx.x;                      // b*(Hn/TH)*(Wn/TW) + ht*(Wn/TW) + wt
    const int wt  = blk % (Wn / TW);
    const int ht  = (blk / (Wn / TW)) % (Hn / TH);
    const int b   = blk / ((Wn / TW) * (Hn / TH));
    const int h0  = ht * TH;
    const int w0  = wt * TW;

    const int tid  = threadIdx.x;
    const int lane = tid & 63;
    const int wave = tid >> 6;                       // 0..15
    const int ph   = wave >> 3;                      // 0..1
    const int pw   = wave & 7;                       // 0..7
    const int h    = h0 + ph;
    const int w    = w0 + pw;

    const int lrow = lane & 15;                      // A row (d within 16) / B f-col
    const int lgrp = lane >> 4;                      // 16B k-slot (c-block)

    const float dv  = *dvp;
    const int   bpc = bp[(b * Hn + h) * Wn + w];

    // ---- per-wave tap shifts & validity (overlaps with staging loads below)
    int  sh[9];
    bool tv[9];
#pragma unroll
    for (int kh = 0; kh < 3; ++kh)
#pragma unroll
        for (int kw = 0; kw < 3; ++kw) {
            const int hh = h - 1 + kh;
            const int ww = w - 1 + kw;
            const bool v = (hh >= 0) && (hh < Hn) && (ww >= 0) && (ww < Wn);
            tv[kh * 3 + kw] = v;
            sh[kh * 3 + kw] = v ? (bpc - bp[(b * Hn + hh) * Wn + ww]) : 0;
        }

    // ---- stage all 40 halo columns once (fp32 -> bf16, swizzled)
    // e = it*1024 + tid; col = e>>9, sl = e&511 (512 ushort4 per column)
    for (int it = 0; it < NCOLS * 512 / 1024; ++it) {
        const int e  = it * 1024 + tid;
        const int j  = e >> 9;
        const int sl = e & 511;
        const int hh = h0 - 1 + j / CW;
        const int ww = w0 - 1 + j % CW;
        if (hh < 0 || hh >= Hn || ww < 0 || ww >= Wn) continue;
        const float4 v = *(const float4*)(img +
            (size_t)((b * Hn + hh) * Wn + ww) * (Dn * Cn) + sl * 4);
        ushort4 u;
        u.x = f2bf(v.x); u.y = f2bf(v.y); u.z = f2bf(v.z); u.w = f2bf(v.w);
        *(ushort4*)&colS[j * (Dn * Cn) + swz_off(sl >> 3, (sl >> 1) & 3) + (sl & 1) * 4] = u;
    }
    __syncthreads();   // the ONLY barrier

    f32x4 acc[4][2];
#pragma unroll
    for (int i = 0; i < 4; ++i)
#pragma unroll
        for (int j = 0; j < 2; ++j) acc[i][j] = (f32x4)0.f;

    // ---- barrier-free compute: 27 taps, 216 MFMA per wave
#pragma unroll
    for (int kh = 0; kh < 3; ++kh) {
#pragma unroll
        for (int kw = 0; kw < 3; ++kw) {
            if (!tv[kh * 3 + kw]) continue;          // sp_valid false -> dv(=0)
            const int s = sh[kh * 3 + kw];
            const ushort* colp = &colS[((ph + kh) * CW + (pw + kw)) * (Dn * Cn)];
#pragma unroll
            for (int kd = 0; kd < 3; ++kd) {
                const int kk = (kh * 3 + kw) * 3 + kd;
                // B frags from global kT (L1-resident, all waves same address)
                const bf16x8 bf0 = *(const bf16x8*)&kT[(kk * Fn + lrow)      * Cn + lgrp * 8];
                const bf16x8 bf1 = *(const bf16x8*)&kT[(kk * Fn + lrow + 16) * Cn + lgrp * 8];
                const int X = s + kd - 1;
                __builtin_amdgcn_s_setprio(1);
#pragma unroll
                for (int dt = 0; dt < 4; ++dt) {
                    const int  idx   = dt * 16 + lrow + X;
                    const int  ci    = idx < 0 ? 0 : (idx > 63 ? 63 : idx);
                    const bool valid = (idx == ci);
                    bf16x8 af = *(const bf16x8*)&colp[swz_off(ci, lgrp)];
                    if (!valid) af = (bf16x8)0;      // OOB depth -> zero (dv=0 path)
                    acc[dt][0] = __builtin_amdgcn_mfma_f32_16x16x32_bf16(af, bf0, acc[dt][0], 0, 0, 0);
                    acc[dt][1] = __builtin_amdgcn_mfma_f32_16x16x32_bf16(af, bf1, acc[dt][1], 0, 0, 0);
                }
                __builtin_amdgcn_s_setprio(0);
            }
        }
    }

    // ---- dv != 0 correction (dead for this benchmark; keeps semantics general)
    if (dv != 0.0f) {
#pragma unroll
        for (int kh = 0; kh < 3; ++kh)
#pragma unroll
            for (int kw = 0; kw < 3; ++kw) {
                const bool sp = tv[kh * 3 + kw];
                const int  s  = sh[kh * 3 + kw];
                for (int kd = 0; kd < 3; ++kd) {
                    float ks0 = 0.f, ks1 = 0.f;
                    for (int c = 0; c < Cn; ++c) {
                        const float* kp = kern + (size_t)(((kh * 3 + kw) * 3 + kd) * Cn + c) * Fn;
                        ks0 += kp[lrow];
                        ks1 += kp[16 + lrow];
                    }
                    for (int dt = 0; dt < 4; ++dt)
                        for (int j = 0; j < 4; ++j) {
                            const int d   = dt * 16 + lgrp * 4 + j;
                            const int idx = d + s + kd - 1;
                            const bool valid = sp && (idx >= 0) && (idx < Dn);
                            if (!valid) { acc[dt][0][j] += dv * ks0; acc[dt][1][j] += dv * ks1; }
                        }
                }
            }
    }

    // ---- epilogue: D lane l reg j -> d = dt*16 + lgrp*4 + j, f = ft*16 + lrow
    const size_t pixbase = ((size_t)(b * Hn + h) * Wn + w) * (Dn * Fn);
#pragma unroll
    for (int dt = 0; dt < 4; ++dt)
#pragma unroll
        for (int ft = 0; ft < 2; ++ft)
#pragma unroll
            for (int j = 0; j < 4; ++j) {
                const int d = dt * 16 + lgrp * 4 + j;
                const int f = ft * 16 + lrow;
                out[pixbase + d * Fn + f] = acc[dt][ft][j];
            }
}

extern "C" void kernel_launch(void* const* d_in, const int* in_sizes, int n_in,
                              void* d_out, int out_size, void* d_ws, size_t ws_size,
                              hipStream_t stream) {
    const float* img  = (const float*)d_in[0];
    const int*   bp   = (const int*)d_in[1];
    const float* kern = (const float*)d_in[2];
    const float* dvp  = (const float*)d_in[3];
    float* out = (float*)d_out;
    ushort* kT = (ushort*)d_ws;                      // 27*32*32*2 = 55296 B

    hipLaunchKernelGGL(prep_kT, dim3(108), dim3(256), 0, stream, kern, kT);

    const int nblk = Bn * (Hn / TH) * (Wn / TW);     // 2*48*16 = 1536
    hipLaunchKernelGGL(sconv3d_mfma, dim3(nblk), dim3(1024), 0, stream,
                       img, bp, kern, kT, dvp, out);
}